// Round 4
// baseline (165.921 us; speedup 1.0000x reference)
//
#include <hip/hip_runtime.h>
#include <hip/hip_bf16.h>

#define Bb 4
#define Tt 1024
#define Ee 768
#define Hh 12
#define Dd 64
#define NTOK (Bb*Tt)   // 4096

// softmax scale 1/sqrt(D)/TEMP folded with log2(e) into Wq/bq so the
// exponential is a bare v_exp_f32 (2^x) on the raw MFMA output.
#define QSCALE 0.18033688f   // 0.125 * log2(e)

typedef __attribute__((ext_vector_type(8))) short bf16x8;  // 8 bf16 in 4 VGPRs
typedef __attribute__((ext_vector_type(4))) float f32x4;   // MFMA accumulator

__device__ __forceinline__ f32x4 mfma16(bf16x8 a, bf16x8 b, f32x4 c) {
  return __builtin_amdgcn_mfma_f32_16x16x32_bf16(a, b, c, 0, 0, 0);
}
__device__ __forceinline__ float exp2x(float x) {
  return __builtin_amdgcn_exp2f(x);
}

// fp32 -> bf16 round-to-nearest-even
__device__ __forceinline__ ushort f2b(float f) {
  uint u = __builtin_bit_cast(uint, f);
  return (ushort)((u + 0x7fffu + ((u >> 16) & 1u)) >> 16);
}
__device__ __forceinline__ uint pack2(float a, float b) {
  return (uint)f2b(a) | ((uint)f2b(b) << 16);
}
__device__ __forceinline__ float b2f(ushort u) {
  return __builtin_bit_cast(float, (uint)u << 16);
}

// async global->LDS, 16B per lane. LDS dest is wave-uniform base + lane*16.
typedef const __attribute__((address_space(1))) void GV;
typedef __attribute__((address_space(3))) void LV;
__device__ __forceinline__ void gload16(const void* g, void* l) {
  __builtin_amdgcn_global_load_lds((GV*)g, (LV*)l, 16, 0, 0);
}

// ---------------- convert: fp32 -> bf16 (* scale), 8 elems/thread --------
struct CvtSeg { const float* src; ushort* dst; int n8; float scale; };
struct CvtArgs { CvtSeg seg[11]; };

__global__ __launch_bounds__(256) void convert_kernel(CvtArgs a) {
  const CvtSeg s = a.seg[blockIdx.y];
  const int i = blockIdx.x * 256 + threadIdx.x;
  if (i >= s.n8) return;
  const float4 v0 = ((const float4*)s.src)[2*i];
  const float4 v1 = ((const float4*)s.src)[2*i + 1];
  uint4 o;
  o.x = pack2(v0.x * s.scale, v0.y * s.scale);
  o.y = pack2(v0.z * s.scale, v0.w * s.scale);
  o.z = pack2(v1.x * s.scale, v1.y * s.scale);
  o.w = pack2(v1.z * s.scale, v1.w * s.scale);
  ((uint4*)s.dst)[i] = o;
}

// ---------------- bf16 GEMM: C[M,N] = A[M,K] @ W[N,K]^T + bias*bscale ----
// m97 structure: 128x128 tile, BK=64, 4 waves (each a 64x64 quadrant, 4x4
// frags), global_load_lds staging with XOR-swizzle (pre-swizzled source +
// swizzled ds_read; involution byte ^= (row&7)<<4 within the 128B row).
template<bool OUT_BF16>
__device__ __forceinline__ void gemm_bf16(
    const ushort* __restrict__ A, const ushort* __restrict__ Bw,
    const float* __restrict__ bias, const float bscale, void* __restrict__ Cp,
    const int K, const int N)
{
  __shared__ ushort Ash[128][64];
  __shared__ ushort Bsh[128][64];
  const int tid  = threadIdx.x;
  const int lane = tid & 63;
  const int wave = tid >> 6;
  const int m0 = blockIdx.x * 128;
  const int n0 = blockIdx.y * 128;
  const int wm = (wave >> 1) << 6;
  const int wn = (wave & 1) << 6;
  const int srow = lane >> 3;                       // 0..7 within 8-row group
  const int scol = ((lane & 7) ^ srow) << 3;        // swizzled element offset
  const ushort* Ag = A  + (size_t)(m0 + wave*8 + srow) * K + scol;
  const ushort* Bg = Bw + (size_t)(n0 + wave*8 + srow) * K + scol;

  f32x4 acc[4][4] = {};
  for (int k0 = 0; k0 < K; k0 += 64) {
    __syncthreads();
#pragma unroll
    for (int rr = 0; rr < 4; rr++) {
      gload16(Ag + (size_t)(rr*32) * K + k0, &Ash[rr*32 + wave*8][0]);
      gload16(Bg + (size_t)(rr*32) * K + k0, &Bsh[rr*32 + wave*8][0]);
    }
    __syncthreads();
#pragma unroll
    for (int kk = 0; kk < 2; kk++) {
      const int pcb = (((lane >> 4) << 4) + kk*64) ^ ((lane & 7) << 4);
      bf16x8 af[4], bfv[4];
#pragma unroll
      for (int m = 0; m < 4; m++)
        af[m] = *(const bf16x8*)((const char*)&Ash[wm + m*16 + (lane & 15)][0] + pcb);
#pragma unroll
      for (int n = 0; n < 4; n++)
        bfv[n] = *(const bf16x8*)((const char*)&Bsh[wn + n*16 + (lane & 15)][0] + pcb);
#pragma unroll
      for (int m = 0; m < 4; m++)
#pragma unroll
        for (int n = 0; n < 4; n++)
          acc[m][n] = mfma16(af[m], bfv[n], acc[m][n]);
    }
  }
  // C/D layout: col = lane&15, row = (lane>>4)*4 + reg  [m89-verified]
#pragma unroll
  for (int n = 0; n < 4; n++) {
    const int col = n0 + wn + n*16 + (lane & 15);
    const float bv = bias[col] * bscale;
#pragma unroll
    for (int m = 0; m < 4; m++) {
#pragma unroll
      for (int r = 0; r < 4; r++) {
        const int row = m0 + wm + m*16 + ((lane >> 4) << 2) + r;
        const float v = acc[m][n][r] + bv;
        if (OUT_BF16) ((ushort*)Cp)[(size_t)row * N + col] = f2b(v);
        else          ((float*)Cp)[(size_t)row * N + col] = v;
      }
    }
  }
}

struct ProjPtrs {
  const ushort* X[5];
  const ushort* W[5];
  const float* b[5];
  float bscale[5];
  ushort* out[5];
};

__global__ __launch_bounds__(256, 2) void proj5_kernel(ProjPtrs p) {
  const int z = blockIdx.z;
  gemm_bf16<true>(p.X[z], p.W[z], p.b[z], p.bscale[z], p.out[z], Ee, Ee);
}

__global__ __launch_bounds__(256, 2) void outproj_kernel(
    const ushort* __restrict__ A, const ushort* __restrict__ W,
    const float* __restrict__ bias, float* __restrict__ C) {
  gemm_bf16<false>(A, W, bias, 1.0f, C, Ee, Ee);
}

// ---------------- Fused attention (single QK^T pass) ----------------
// Global-flat softmax: O = sum_j c_j * (exp2(St_j) V), c_j = T/(3 Z_j),
// Z_j = sum over all (t,s). This kernel computes unnormalized U_j and Z_j
// in ONE pass; a combine kernel applies c_j afterwards.
// U_j is written IN-PLACE over q_j: each block reads exactly its own q
// region into registers at start and writes the same region at the end.
// QK is computed operand-swapped (S^T = mfma(K,Q)) so each lane's 4 C-regs
// are 4 consecutive s for one t -> P write is ds_write_b64, not 4x b16.
__global__ __launch_bounds__(256, 3) void attn_fused(
    ushort* qu1, ushort* qu2, ushort* qu3,
    const ushort* __restrict__ kmat, const ushort* __restrict__ vmat,
    float* __restrict__ Z)
{
  const int bh = blockIdx.x;
  const int b = bh / Hh, h = bh % Hh;
  const int lane = threadIdx.x & 63;
  const int wave = threadIdx.x >> 6;
  const int trow0 = blockIdx.y * 64 + wave * 16;

  __shared__ ushort Ksh[64][64];   // gload_lds, XOR-swizzled content
  __shared__ ushort Vsh[64][72];   // transposed [d][s]; PV B-frag k-contiguous
  __shared__ ushort Psh[64][72];   // P row-major [t][s]; reused across j

  const int srow = lane >> 3;
  const int scolb = ((lane & 7) ^ srow) << 4;
  const ushort* Kg = kmat + (size_t)(b*Tt)*Ee + h*Dd;

  ushort* qs[3] = {qu1, qu2, qu3};
  bf16x8 qf[3][2];   // B-frag: col t = lane&15, k(d) = kk*32+(lane>>4)*8
#pragma unroll
  for (int j = 0; j < 3; j++)
#pragma unroll
    for (int kk = 0; kk < 2; kk++) {
      const int t = trow0 + (lane & 15);
      const int d = kk*32 + ((lane >> 4) << 3);
      qf[j][kk] = *(const bf16x8*)(qs[j] + ((size_t)(b*Tt + t))*Ee + h*Dd + d);
    }

  float zacc[3] = {0.f, 0.f, 0.f};
  f32x4 uacc[3][4] = {};

  for (int s0 = 0; s0 < Tt; s0 += 64) {
    __syncthreads();
#pragma unroll
    for (int rr = 0; rr < 2; rr++) {
      const int rowbase = rr*32 + wave*8;
      gload16((const char*)(Kg + (size_t)(s0 + rowbase + srow)*Ee) + scolb,
              &Ksh[rowbase][0]);
    }
    for (int i = threadIdx.x; i < 512; i += 256) {   // V tile, transposed
      const int r = i & 63;              // s row
      const int c = (i >> 6) << 3;       // d offset
      bf16x8 v = *(const bf16x8*)(vmat + ((size_t)(b*Tt + s0 + r))*Ee + h*Dd + c);
#pragma unroll
      for (int u = 0; u < 8; u++) Vsh[c + u][r] = (ushort)v[u];
    }
    __syncthreads();

    // QK^T swapped: sacc[j][n] = S^T, rows s (n*16 block), col t = lane&15
    f32x4 sacc[3][4] = {};
#pragma unroll
    for (int kk = 0; kk < 2; kk++) {
      bf16x8 kf[4];   // A-frag: row s = lane&15, k(d) contiguous
#pragma unroll
      for (int n = 0; n < 4; n++)
        kf[n] = *(const bf16x8*)((const char*)&Ksh[n*16 + (lane & 15)][0] +
                  ((((lane >> 4) << 4) + kk*64) ^ ((lane & 7) << 4)));
#pragma unroll
      for (int j = 0; j < 3; j++)
#pragma unroll
        for (int n = 0; n < 4; n++)
          sacc[j][n] = mfma16(kf[n], qf[j][kk], sacc[j][n]);
    }

    // cache V B-frags for reuse across the 3 j's
    bf16x8 vb[2][4];
#pragma unroll
    for (int kk = 0; kk < 2; kk++)
#pragma unroll
      for (int n = 0; n < 4; n++)
        vb[kk][n] = *(const bf16x8*)&Vsh[n*16 + (lane & 15)][kk*32 + ((lane >> 4) << 3)];

    const int prow = wave*16 + (lane & 15);
#pragma unroll
    for (int j = 0; j < 3; j++) {
      float zl = 0.f;
#pragma unroll
      for (int n = 0; n < 4; n++) {
        const float e0 = exp2x(sacc[j][n][0]);
        const float e1 = exp2x(sacc[j][n][1]);
        const float e2 = exp2x(sacc[j][n][2]);
        const float e3 = exp2x(sacc[j][n][3]);
        zl += (e0 + e1) + (e2 + e3);
        *(uint2*)&Psh[prow][n*16 + ((lane >> 4) << 2)] =
            make_uint2(pack2(e0, e1), pack2(e2, e3));
      }
      zacc[j] += zl;
      // PV for this j: A-frag from own-wave Psh rows, B-frag cached
#pragma unroll
      for (int kk = 0; kk < 2; kk++) {
        const bf16x8 pa = *(const bf16x8*)&Psh[wave*16 + (lane & 15)]
                                              [kk*32 + ((lane >> 4) << 3)];
#pragma unroll
        for (int n = 0; n < 4; n++)
          uacc[j][n] = mfma16(pa, vb[kk][n], uacc[j][n]);
      }
    }
  }

  // epilogue: U_j (bf16, in-place over q_j) and Z atomics
#pragma unroll
  for (int j = 0; j < 3; j++)
#pragma unroll
    for (int n = 0; n < 4; n++)
#pragma unroll
      for (int r = 0; r < 4; r++) {
        const int t = trow0 + ((lane >> 4) << 2) + r;
        const int d = n*16 + (lane & 15);
        qs[j][((size_t)(b*Tt + t))*Ee + h*Dd + d] = f2b(uacc[j][n][r]);
      }
#pragma unroll
  for (int j = 0; j < 3; j++) {
    float v = zacc[j];
#pragma unroll
    for (int off = 32; off > 0; off >>= 1) v += __shfl_xor(v, off, 64);
    if (lane == 0) atomicAdd(&Z[bh*3 + j], v);
  }
}

// ---------------- combine: O = sum_j c_j U_j (bf16 in, bf16 out) --------
__global__ __launch_bounds__(256) void combine_kernel(
    const ushort* __restrict__ U1, const ushort* __restrict__ U2,
    const ushort* __restrict__ U3, const float* __restrict__ Z,
    ushort* __restrict__ O)
{
  const int i = blockIdx.x * 256 + threadIdx.x;   // one ushort4 per thread
  const int e4 = i << 2;
  const int ecol = e4 % Ee;
  const int b = e4 / (Ee * Tt);
  const int bh3 = (b * Hh + ecol / Dd) * 3;
  const float c1 = (float)Tt / (3.0f * Z[bh3 + 0]);
  const float c2 = (float)Tt / (3.0f * Z[bh3 + 1]);
  const float c3 = (float)Tt / (3.0f * Z[bh3 + 2]);
  const ushort4 u1 = *(const ushort4*)(U1 + e4);
  const ushort4 u2 = *(const ushort4*)(U2 + e4);
  const ushort4 u3 = *(const ushort4*)(U3 + e4);
  ushort4 o;
  o.x = f2b(c1*b2f(u1.x) + c2*b2f(u2.x) + c3*b2f(u3.x));
  o.y = f2b(c1*b2f(u1.y) + c2*b2f(u2.y) + c3*b2f(u3.y));
  o.z = f2b(c1*b2f(u1.z) + c2*b2f(u2.z) + c3*b2f(u3.z));
  o.w = f2b(c1*b2f(u1.w) + c2*b2f(u2.w) + c3*b2f(u3.w));
  *(ushort4*)(O + e4) = o;
}

extern "C" void kernel_launch(void* const* d_in, const int* in_sizes, int n_in,
                              void* d_out, int out_size, void* d_ws, size_t ws_size,
                              hipStream_t stream) {
  const float* X[5];
  for (int i = 0; i < 5; i++) X[i] = (const float*)d_in[i];
  const float* W[6];  const float* bias[6];
  for (int j = 0; j < 6; j++) {
    W[j]    = (const float*)d_in[5 + 2*j];
    bias[j] = (const float*)d_in[6 + 2*j];
  }

  char* ws = (char*)d_ws;
  const size_t segX = (size_t)NTOK * Ee * sizeof(ushort);   // 6.29 MB
  const size_t segW = (size_t)Ee * Ee * sizeof(ushort);     // 1.18 MB
  ushort* Xbf[5];
  for (int i = 0; i < 5; i++) Xbf[i] = (ushort*)(ws + i*segX);
  ushort* Wbf[6];
  for (int j = 0; j < 6; j++) Wbf[j] = (ushort*)(ws + 5*segX + j*segW);
  ushort* Pout[5];
  for (int i = 0; i < 5; i++) Pout[i] = (ushort*)(ws + 5*segX + 6*segW + i*segX);
  ushort* Ob = Xbf[0];   // Xbf dead after proj5; reuse for attention output
  float*  Zp = (float*)(ws + 10*segX + 6*segW);

  CvtArgs ca;
  for (int i = 0; i < 5; i++) ca.seg[i]     = {X[i], Xbf[i], NTOK*Ee/8, 1.0f};
  for (int j = 0; j < 6; j++) ca.seg[5 + j] = {W[j], Wbf[j], Ee*Ee/8,
                                               (j < 3) ? QSCALE : 1.0f};

  ProjPtrs pp;
  for (int i = 0; i < 5; i++) {
    pp.X[i] = Xbf[i]; pp.W[i] = Wbf[i]; pp.b[i] = bias[i]; pp.out[i] = Pout[i];
    pp.bscale[i] = (i < 3) ? QSCALE : 1.0f;
  }

  hipMemsetAsync(Zp, 0, 48*3*sizeof(float), stream);
  convert_kernel<<<dim3(1536, 11), 256, 0, stream>>>(ca);
  proj5_kernel<<<dim3(32, 6, 5), 256, 0, stream>>>(pp);
  // fused pass: writes U_j in place over q_j (Pout[0..2]), Z into Zp
  attn_fused<<<dim3(48, 16), 256, 0, stream>>>(Pout[0], Pout[1], Pout[2],
                                               Pout[3], Pout[4], Zp);
  combine_kernel<<<dim3((NTOK*Ee/4)/256), 256, 0, stream>>>(
      Pout[0], Pout[1], Pout[2], Zp, Ob);
  outproj_kernel<<<dim3(32, 6), 256, 0, stream>>>(Ob, Wbf[5], bias[5], (float*)d_out);
}